// Round 5
// baseline (1942.527 us; speedup 1.0000x reference)
//
#include <hip/hip_runtime.h>

typedef __attribute__((ext_vector_type(8))) short bf16x8;
typedef __attribute__((ext_vector_type(16))) float f32x16;

#define SEQ 16
#define NAG 128
#define HD  512

__device__ __forceinline__ unsigned short f2bf(float x) {
  unsigned int u = __float_as_uint(x);
  return (unsigned short)((u + 0x7fffu + ((u >> 16) & 1u)) >> 16);  // RNE
}
__device__ __forceinline__ float sigm(float x) { return 1.0f / (1.0f + __expf(-x)); }
__device__ __forceinline__ float tanh_(float x) { return 2.0f / (1.0f + __expf(-2.0f * x)) - 1.0f; }

// Pack weights into 32x32 MFMA-B-fragment order:
//   Wpk[tile*32768 + (ks*64 + lane)*8 + e]
//   col = tile*32 + (lane&31), k = ks*16 + (lane>>5)*8 + e ; tile in [0,64), ks in [0,64)
//   k < 512 -> W_ih[:,k], else W_hh[:,k-512].  bsum[n] = b_ih[n]+b_hh[n].
__global__ void prep_pack32(const float* __restrict__ Wih, const float* __restrict__ Whh,
                            const float* __restrict__ bih, const float* __restrict__ bhh,
                            unsigned short* __restrict__ Wpk, float* __restrict__ bsum) {
  const int t  = blockIdx.x >> 6;
  const int ks = blockIdx.x & 63;
  const int l  = threadIdx.x;
  const int n  = t * 32 + (l & 31);
  const int k  = ks * 16 + (l >> 5) * 8;
  const float* p = (k < 512) ? (Wih + (size_t)n * 512 + k) : (Whh + (size_t)n * 512 + (k - 512));
  float4 w0 = *(const float4*)p;
  float4 w1 = *(const float4*)(p + 4);
  bf16x8 v = {(short)f2bf(w0.x), (short)f2bf(w0.y), (short)f2bf(w0.z), (short)f2bf(w0.w),
              (short)f2bf(w1.x), (short)f2bf(w1.y), (short)f2bf(w1.z), (short)f2bf(w1.w)};
  *(bf16x8*)(Wpk + ((size_t)blockIdx.x * 64 + l) * 8) = v;
  if (ks == 0 && l < 32) bsum[n] = bih[n] + bhh[n];
}

template <bool PACKED>
__device__ __forceinline__ bf16x8 loadBf(const float* __restrict__ Wih,
                                         const float* __restrict__ Whh,
                                         int tile, int ks, int lane) {
  int n = tile * 32 + (lane & 31);
  int k = ks * 16 + (lane >> 5) * 8;
  const float* p = (k < 512) ? (Wih + (size_t)n * 512 + k) : (Whh + (size_t)n * 512 + (k - 512));
  float4 w0 = *(const float4*)p;
  float4 w1 = *(const float4*)(p + 4);
  return bf16x8{(short)f2bf(w0.x), (short)f2bf(w0.y), (short)f2bf(w0.z), (short)f2bf(w0.w),
                (short)f2bf(w1.x), (short)f2bf(w1.y), (short)f2bf(w1.z), (short)f2bf(w1.w)};
}

template <bool PACKED>
__global__ __launch_bounds__(512, 2)
void lstm_d8(const float* __restrict__ hxs, const float* __restrict__ cxs,
             const float* __restrict__ h_self, const float* __restrict__ h_inter,
             const int* __restrict__ reset,
             const unsigned short* __restrict__ Wpk, const float* __restrict__ bsum,
             const float* __restrict__ Wih, const float* __restrict__ Whh,
             const float* __restrict__ bih, const float* __restrict__ bhh,
             float* __restrict__ out) {
  __shared__ __align__(16) unsigned short x_lds[32 * 512];      // 32 KB
  __shared__ __align__(16) unsigned short h_lds[2][32 * 512];   // 64 KB

  const int tid  = threadIdx.x;
  const int w    = tid >> 6;
  const int lane = tid & 63;
  const int colB = lane & 31;
  const int khB  = lane >> 5;
  const int row  = colB;                 // A-row this lane reads
  const int asw  = (row & 31) << 3;      // full 32-row XOR swizzle (R3: 0 conflicts)

  const int bid = blockIdx.x, traj = bid >> 2, agent0 = (bid & 3) * 32;
  const int rS = tid >> 4, l16 = tid & 15;
  const int swS = (rS & 31) << 3;
  const size_t CYS = (size_t)SEQ * 64 * NAG * HD;  // 67108864

  { // stage h(0) from hxs
    const float* src = hxs + ((size_t)traj * SEQ * NAG + (agent0 + rS)) * HD;
    #pragma unroll
    for (int p = 0; p < 8; ++p) {
      int k = p * 64 + l16 * 4;
      float4 v = *(const float4*)(src + k);
      *(ushort4*)&h_lds[0][rS * 512 + (k ^ swS)] =
          make_ushort4(f2bf(v.x), f2bf(v.y), f2bf(v.z), f2bf(v.w));
    }
  }

  // persistent per-lane state
  float c_reg[2][16];
  float biasv[2][4];
  {
    #pragma unroll
    for (int u = 0; u < 2; ++u)
      #pragma unroll
      for (int q = 0; q < 4; ++q) {
        int n = q * 512 + w * 64 + u * 32 + colB;
        biasv[u][q] = PACKED ? bsum[n] : (bih[n] + bhh[n]);
      }
    const size_t cbase = ((size_t)traj * SEQ * NAG + agent0) * HD;
    #pragma unroll
    for (int u = 0; u < 2; ++u)
      #pragma unroll
      for (int reg = 0; reg < 16; ++reg) {
        int r = (reg & 3) + 8 * (reg >> 2) + 4 * khB;
        c_reg[u][reg] = cxs[cbase + (size_t)r * HD + w * 64 + u * 32 + colB];
      }
  }

  for (int t = 0; t < SEQ; ++t) {
    const int b  = traj * SEQ + t;
    const int mt = 1 - reset[b];
    const unsigned short* hcur = h_lds[t & 1];
    unsigned short*       hnxt = h_lds[(t & 1) ^ 1];

    { // stage x(t) = [h_self[b][:,256:] | h_inter[b]] -> bf16
      const float* srcs = h_self  + ((size_t)b * NAG + (agent0 + rS)) * HD + 256;
      const float* srci = h_inter + ((size_t)b * NAG + (agent0 + rS)) * 256;
      #pragma unroll
      for (int p = 0; p < 8; ++p) {
        int k = p * 64 + l16 * 4;
        const float* sp = (k < 256) ? (srcs + k) : (srci + (k - 256));
        float4 v = *(const float4*)sp;
        *(ushort4*)&x_lds[rS * 512 + (k ^ swS)] =
            make_ushort4(f2bf(v.x), f2bf(v.y), f2bf(v.z), f2bf(v.w));
      }
      if (mt == 0) {  // h input of this step is exactly zero
        uint4* pz = (uint4*)h_lds[t & 1];
        #pragma unroll
        for (int i = 0; i < 4; ++i) pz[tid + i * 512] = uint4{0, 0, 0, 0};
      }
    }
    __syncthreads();

    auto lda = [&](int ks, const unsigned short* src) -> bf16x8 {
      int kk = (ks & 31) * 16 + khB * 8;
      return *(const bf16x8*)(src + row * 512 + (kk ^ asw));
    };

    #pragma unroll
    for (int u = 0; u < 2; ++u) {
      const int t0 = w * 2 + u, t1 = 16 + w * 2 + u, t2 = 32 + w * 2 + u, t3 = 48 + w * 2 + u;
      f32x16 acc[4];
      #pragma unroll
      for (int q = 0; q < 4; ++q)
        #pragma unroll
        for (int e = 0; e < 16; ++e) acc[q][e] = biasv[u][q];

      bf16x8 Bq[8][4];  // depth-8 prefetch queue, statically indexed only
      auto ldB = [&](bf16x8* B, int ks) {
        if (PACKED) {
          const size_t off = ((size_t)ks * 64 + lane) * 8;
          B[0] = *(const bf16x8*)(Wpk + (size_t)t0 * 32768 + off);
          B[1] = *(const bf16x8*)(Wpk + (size_t)t1 * 32768 + off);
          B[2] = *(const bf16x8*)(Wpk + (size_t)t2 * 32768 + off);
          B[3] = *(const bf16x8*)(Wpk + (size_t)t3 * 32768 + off);
        } else {
          B[0] = loadBf<PACKED>(Wih, Whh, t0, ks, lane);
          B[1] = loadBf<PACKED>(Wih, Whh, t1, ks, lane);
          B[2] = loadBf<PACKED>(Wih, Whh, t2, ks, lane);
          B[3] = loadBf<PACKED>(Wih, Whh, t3, ks, lane);
        }
      };

      // prologue: fill queue with ks 0..7
      #pragma unroll
      for (int d = 0; d < 8; ++d) ldB(Bq[d], d);

      // x half: ks 0..31, prefetch ks+8 (8..39)
      #pragma unroll 1
      for (int kp = 0; kp < 4; ++kp) {
        #pragma unroll
        for (int d = 0; d < 8; ++d) {
          const int ks = kp * 8 + d;
          bf16x8 a = lda(ks, x_lds);
          __builtin_amdgcn_s_setprio(1);
          acc[0] = __builtin_amdgcn_mfma_f32_32x32x16_bf16(a, Bq[d][0], acc[0], 0, 0, 0);
          acc[1] = __builtin_amdgcn_mfma_f32_32x32x16_bf16(a, Bq[d][1], acc[1], 0, 0, 0);
          acc[2] = __builtin_amdgcn_mfma_f32_32x32x16_bf16(a, Bq[d][2], acc[2], 0, 0, 0);
          acc[3] = __builtin_amdgcn_mfma_f32_32x32x16_bf16(a, Bq[d][3], acc[3], 0, 0, 0);
          __builtin_amdgcn_s_setprio(0);
          ldB(Bq[d], ks + 8);
        }
      }
      // h half with prefetch: ks 32..55, prefetch ks+8 (40..63)
      #pragma unroll 1
      for (int kp = 0; kp < 3; ++kp) {
        #pragma unroll
        for (int d = 0; d < 8; ++d) {
          const int ks = 32 + kp * 8 + d;
          bf16x8 a = lda(ks, hcur);
          __builtin_amdgcn_s_setprio(1);
          acc[0] = __builtin_amdgcn_mfma_f32_32x32x16_bf16(a, Bq[d][0], acc[0], 0, 0, 0);
          acc[1] = __builtin_amdgcn_mfma_f32_32x32x16_bf16(a, Bq[d][1], acc[1], 0, 0, 0);
          acc[2] = __builtin_amdgcn_mfma_f32_32x32x16_bf16(a, Bq[d][2], acc[2], 0, 0, 0);
          acc[3] = __builtin_amdgcn_mfma_f32_32x32x16_bf16(a, Bq[d][3], acc[3], 0, 0, 0);
          __builtin_amdgcn_s_setprio(0);
          ldB(Bq[d], ks + 8);
        }
      }
      // tail: ks 56..63, queue drain (no loads)
      #pragma unroll
      for (int d = 0; d < 8; ++d) {
        const int ks = 56 + d;
        bf16x8 a = lda(ks, hcur);
        __builtin_amdgcn_s_setprio(1);
        acc[0] = __builtin_amdgcn_mfma_f32_32x32x16_bf16(a, Bq[d][0], acc[0], 0, 0, 0);
        acc[1] = __builtin_amdgcn_mfma_f32_32x32x16_bf16(a, Bq[d][1], acc[1], 0, 0, 0);
        acc[2] = __builtin_amdgcn_mfma_f32_32x32x16_bf16(a, Bq[d][2], acc[2], 0, 0, 0);
        acc[3] = __builtin_amdgcn_mfma_f32_32x32x16_bf16(a, Bq[d][3], acc[3], 0, 0, 0);
        __builtin_amdgcn_s_setprio(0);
      }

      // LSTM cell: lane-local i/f/g/o at same (row, hd); bias already in acc
      const int hd = w * 64 + u * 32 + colB;
      #pragma unroll
      for (int reg = 0; reg < 16; ++reg) {
        float gi = acc[0][reg], gf = acc[1][reg], gg = acc[2][reg], go = acc[3][reg];
        float cp = mt ? c_reg[u][reg] : 0.0f;
        float cn = sigm(gf) * cp + sigm(gi) * tanh_(gg);
        float hn = sigm(go) * tanh_(cn);
        c_reg[u][reg] = cn;
        int r = (reg & 3) + 8 * (reg >> 2) + 4 * khB;
        size_t ob = ((size_t)b * NAG + agent0 + r) * HD + hd;
        out[ob] = hn;
        out[CYS + ob] = cn;
        hnxt[r * 512 + (hd ^ ((r & 31) << 3))] = f2bf(hn);
      }
    }
    __syncthreads();
  }
}

extern "C" void kernel_launch(void* const* d_in, const int* in_sizes, int n_in,
                              void* d_out, int out_size, void* d_ws, size_t ws_size,
                              hipStream_t stream) {
  (void)in_sizes; (void)n_in; (void)out_size;
  const float* hxs     = (const float*)d_in[1];
  const float* cxs     = (const float*)d_in[2];
  const float* h_self  = (const float*)d_in[3];
  const float* h_inter = (const float*)d_in[4];
  const int*   reset   = (const int*)d_in[5];
  const float* Wih     = (const float*)d_in[6];
  const float* Whh     = (const float*)d_in[7];
  const float* bih     = (const float*)d_in[8];
  const float* bhh     = (const float*)d_in[9];
  float* out = (float*)d_out;

  const size_t needW = (size_t)2048 * 1024 * sizeof(unsigned short);  // 4 MB
  const size_t need  = needW + 8192;

  if (d_ws != nullptr && ws_size >= need) {
    unsigned short* Wpk  = (unsigned short*)d_ws;
    float*          bsum = (float*)((char*)d_ws + needW);
    prep_pack32<<<4096, 64, 0, stream>>>(Wih, Whh, bih, bhh, Wpk, bsum);
    lstm_d8<true><<<256, 512, 0, stream>>>(hxs, cxs, h_self, h_inter, reset,
                                           Wpk, bsum, Wih, Whh, bih, bhh, out);
  } else {
    lstm_d8<false><<<256, 512, 0, stream>>>(hxs, cxs, h_self, h_inter, reset,
                                            nullptr, nullptr, Wih, Whh, bih, bhh, out);
  }
}

// Round 6
// 1903.915 us; speedup vs baseline: 1.0203x; 1.0203x over previous
//
#include <hip/hip_runtime.h>

typedef __attribute__((ext_vector_type(8))) short bf16x8;
typedef __attribute__((ext_vector_type(16))) float f32x16;

#define SEQ 16
#define NAG 128
#define HD  512

__device__ __forceinline__ unsigned short f2bf(float x) {
  unsigned int u = __float_as_uint(x);
  return (unsigned short)((u + 0x7fffu + ((u >> 16) & 1u)) >> 16);  // RNE
}
__device__ __forceinline__ float sigm(float x) { return 1.0f / (1.0f + __expf(-x)); }
__device__ __forceinline__ float tanh_(float x) { return 2.0f / (1.0f + __expf(-2.0f * x)) - 1.0f; }

// Pack weights into 32x32 MFMA-B-fragment order:
//   Wpk[tile*32768 + (ks*64 + lane)*8 + e]
//   col = tile*32 + (lane&31), k = ks*16 + (lane>>5)*8 + e ; tile in [0,64), ks in [0,64)
//   k < 512 -> W_ih[:,k], else W_hh[:,k-512].  bsum[n] = b_ih[n]+b_hh[n].
__global__ void prep_pack32(const float* __restrict__ Wih, const float* __restrict__ Whh,
                            const float* __restrict__ bih, const float* __restrict__ bhh,
                            unsigned short* __restrict__ Wpk, float* __restrict__ bsum) {
  const int t  = blockIdx.x >> 6;
  const int ks = blockIdx.x & 63;
  const int l  = threadIdx.x;
  const int n  = t * 32 + (l & 31);
  const int k  = ks * 16 + (l >> 5) * 8;
  const float* p = (k < 512) ? (Wih + (size_t)n * 512 + k) : (Whh + (size_t)n * 512 + (k - 512));
  float4 w0 = *(const float4*)p;
  float4 w1 = *(const float4*)(p + 4);
  bf16x8 v = {(short)f2bf(w0.x), (short)f2bf(w0.y), (short)f2bf(w0.z), (short)f2bf(w0.w),
              (short)f2bf(w1.x), (short)f2bf(w1.y), (short)f2bf(w1.z), (short)f2bf(w1.w)};
  *(bf16x8*)(Wpk + ((size_t)blockIdx.x * 64 + l) * 8) = v;
  if (ks == 0 && l < 32) bsum[n] = bih[n] + bhh[n];
}

template <bool PACKED>
__device__ __forceinline__ bf16x8 loadBf(const float* __restrict__ Wih,
                                         const float* __restrict__ Whh,
                                         int tile, int ks, int lane) {
  int n = tile * 32 + (lane & 31);
  int k = ks * 16 + (lane >> 5) * 8;
  const float* p = (k < 512) ? (Wih + (size_t)n * 512 + k) : (Whh + (size_t)n * 512 + (k - 512));
  float4 w0 = *(const float4*)p;
  float4 w1 = *(const float4*)(p + 4);
  return bf16x8{(short)f2bf(w0.x), (short)f2bf(w0.y), (short)f2bf(w0.z), (short)f2bf(w0.w),
                (short)f2bf(w1.x), (short)f2bf(w1.y), (short)f2bf(w1.z), (short)f2bf(w1.w)};
}

// 1 block/CU (LDS=96KB forces this anyway) -> 256-VGPR budget, no spill.
template <bool PACKED>
__global__ __launch_bounds__(512, 1)
void lstm_d8(const float* __restrict__ hxs, const float* __restrict__ cxs,
             const float* __restrict__ h_self, const float* __restrict__ h_inter,
             const int* __restrict__ reset,
             const unsigned short* __restrict__ Wpk, const float* __restrict__ bsum,
             const float* __restrict__ Wih, const float* __restrict__ Whh,
             const float* __restrict__ bih, const float* __restrict__ bhh,
             float* __restrict__ out) {
  __shared__ __align__(16) unsigned short x_lds[32 * 512];      // 32 KB
  __shared__ __align__(16) unsigned short h_lds[2][32 * 512];   // 64 KB

  const int tid  = threadIdx.x;
  const int w    = tid >> 6;
  const int lane = tid & 63;
  const int colB = lane & 31;
  const int khB  = lane >> 5;
  const int row  = colB;                 // A-row this lane reads
  const int asw  = (row & 31) << 3;      // full 32-row XOR swizzle (0 conflicts, R3/R5)

  const int bid = blockIdx.x, traj = bid >> 2, agent0 = (bid & 3) * 32;
  const int rS = tid >> 4, l16 = tid & 15;
  const int swS = (rS & 31) << 3;
  const size_t CYS = (size_t)SEQ * 64 * NAG * HD;  // 67108864

  { // stage h(0) from hxs
    const float* src = hxs + ((size_t)traj * SEQ * NAG + (agent0 + rS)) * HD;
    #pragma unroll
    for (int p = 0; p < 8; ++p) {
      int k = p * 64 + l16 * 4;
      float4 v = *(const float4*)(src + k);
      *(ushort4*)&h_lds[0][rS * 512 + (k ^ swS)] =
          make_ushort4(f2bf(v.x), f2bf(v.y), f2bf(v.z), f2bf(v.w));
    }
  }

  // persistent per-lane state
  float c_reg[2][16];
  float biasv[2][4];
  {
    #pragma unroll
    for (int u = 0; u < 2; ++u)
      #pragma unroll
      for (int q = 0; q < 4; ++q) {
        int n = q * 512 + w * 64 + u * 32 + colB;
        biasv[u][q] = PACKED ? bsum[n] : (bih[n] + bhh[n]);
      }
    const size_t cbase = ((size_t)traj * SEQ * NAG + agent0) * HD;
    #pragma unroll
    for (int u = 0; u < 2; ++u)
      #pragma unroll
      for (int reg = 0; reg < 16; ++reg) {
        int r = (reg & 3) + 8 * (reg >> 2) + 4 * khB;
        c_reg[u][reg] = cxs[cbase + (size_t)r * HD + w * 64 + u * 32 + colB];
      }
  }

  for (int t = 0; t < SEQ; ++t) {
    const int b  = traj * SEQ + t;
    const int mt = 1 - reset[b];
    const unsigned short* hcur = h_lds[t & 1];
    unsigned short*       hnxt = h_lds[(t & 1) ^ 1];

    { // stage x(t) = [h_self[b][:,256:] | h_inter[b]] -> bf16
      const float* srcs = h_self  + ((size_t)b * NAG + (agent0 + rS)) * HD + 256;
      const float* srci = h_inter + ((size_t)b * NAG + (agent0 + rS)) * 256;
      #pragma unroll
      for (int p = 0; p < 8; ++p) {
        int k = p * 64 + l16 * 4;
        const float* sp = (k < 256) ? (srcs + k) : (srci + (k - 256));
        float4 v = *(const float4*)sp;
        *(ushort4*)&x_lds[rS * 512 + (k ^ swS)] =
            make_ushort4(f2bf(v.x), f2bf(v.y), f2bf(v.z), f2bf(v.w));
      }
      if (mt == 0) {  // h input of this step is exactly zero
        uint4* pz = (uint4*)h_lds[t & 1];
        #pragma unroll
        for (int i = 0; i < 4; ++i) pz[tid + i * 512] = uint4{0, 0, 0, 0};
      }
    }
    __syncthreads();

    auto lda = [&](int ks, const unsigned short* src) -> bf16x8 {
      int kk = (ks & 31) * 16 + khB * 8;
      return *(const bf16x8*)(src + row * 512 + (kk ^ asw));
    };

    #pragma unroll
    for (int u = 0; u < 2; ++u) {
      const int t0 = w * 2 + u, t1 = 16 + w * 2 + u, t2 = 32 + w * 2 + u, t3 = 48 + w * 2 + u;
      f32x16 acc[4];
      #pragma unroll
      for (int q = 0; q < 4; ++q)
        #pragma unroll
        for (int e = 0; e < 16; ++e) acc[q][e] = biasv[u][q];

      bf16x8 Bq[8][4];  // depth-8 prefetch queue, statically indexed only
      auto ldB = [&](bf16x8* B, int ks) {
        if (PACKED) {
          const size_t off = ((size_t)ks * 64 + lane) * 8;
          B[0] = *(const bf16x8*)(Wpk + (size_t)t0 * 32768 + off);
          B[1] = *(const bf16x8*)(Wpk + (size_t)t1 * 32768 + off);
          B[2] = *(const bf16x8*)(Wpk + (size_t)t2 * 32768 + off);
          B[3] = *(const bf16x8*)(Wpk + (size_t)t3 * 32768 + off);
        } else {
          B[0] = loadBf<PACKED>(Wih, Whh, t0, ks, lane);
          B[1] = loadBf<PACKED>(Wih, Whh, t1, ks, lane);
          B[2] = loadBf<PACKED>(Wih, Whh, t2, ks, lane);
          B[3] = loadBf<PACKED>(Wih, Whh, t3, ks, lane);
        }
      };

      // prologue: fill queue with ks 0..7
      #pragma unroll
      for (int d = 0; d < 8; ++d) ldB(Bq[d], d);

      // x half: ks 0..31, prefetch ks+8 (8..39)
      #pragma unroll 1
      for (int kp = 0; kp < 4; ++kp) {
        #pragma unroll
        for (int d = 0; d < 8; ++d) {
          const int ks = kp * 8 + d;
          bf16x8 a = lda(ks, x_lds);
          __builtin_amdgcn_s_setprio(1);
          acc[0] = __builtin_amdgcn_mfma_f32_32x32x16_bf16(a, Bq[d][0], acc[0], 0, 0, 0);
          acc[1] = __builtin_amdgcn_mfma_f32_32x32x16_bf16(a, Bq[d][1], acc[1], 0, 0, 0);
          acc[2] = __builtin_amdgcn_mfma_f32_32x32x16_bf16(a, Bq[d][2], acc[2], 0, 0, 0);
          acc[3] = __builtin_amdgcn_mfma_f32_32x32x16_bf16(a, Bq[d][3], acc[3], 0, 0, 0);
          __builtin_amdgcn_s_setprio(0);
          ldB(Bq[d], ks + 8);
        }
      }
      // h half with prefetch: ks 32..55, prefetch ks+8 (40..63)
      #pragma unroll 1
      for (int kp = 0; kp < 3; ++kp) {
        #pragma unroll
        for (int d = 0; d < 8; ++d) {
          const int ks = 32 + kp * 8 + d;
          bf16x8 a = lda(ks, hcur);
          __builtin_amdgcn_s_setprio(1);
          acc[0] = __builtin_amdgcn_mfma_f32_32x32x16_bf16(a, Bq[d][0], acc[0], 0, 0, 0);
          acc[1] = __builtin_amdgcn_mfma_f32_32x32x16_bf16(a, Bq[d][1], acc[1], 0, 0, 0);
          acc[2] = __builtin_amdgcn_mfma_f32_32x32x16_bf16(a, Bq[d][2], acc[2], 0, 0, 0);
          acc[3] = __builtin_amdgcn_mfma_f32_32x32x16_bf16(a, Bq[d][3], acc[3], 0, 0, 0);
          __builtin_amdgcn_s_setprio(0);
          ldB(Bq[d], ks + 8);
        }
      }
      // tail: ks 56..63, queue drain (no loads)
      #pragma unroll
      for (int d = 0; d < 8; ++d) {
        const int ks = 56 + d;
        bf16x8 a = lda(ks, hcur);
        __builtin_amdgcn_s_setprio(1);
        acc[0] = __builtin_amdgcn_mfma_f32_32x32x16_bf16(a, Bq[d][0], acc[0], 0, 0, 0);
        acc[1] = __builtin_amdgcn_mfma_f32_32x32x16_bf16(a, Bq[d][1], acc[1], 0, 0, 0);
        acc[2] = __builtin_amdgcn_mfma_f32_32x32x16_bf16(a, Bq[d][2], acc[2], 0, 0, 0);
        acc[3] = __builtin_amdgcn_mfma_f32_32x32x16_bf16(a, Bq[d][3], acc[3], 0, 0, 0);
        __builtin_amdgcn_s_setprio(0);
      }

      // LSTM cell: lane-local i/f/g/o at same (row, hd); bias already in acc
      const int hd = w * 64 + u * 32 + colB;
      #pragma unroll
      for (int reg = 0; reg < 16; ++reg) {
        float gi = acc[0][reg], gf = acc[1][reg], gg = acc[2][reg], go = acc[3][reg];
        float cp = mt ? c_reg[u][reg] : 0.0f;
        float cn = sigm(gf) * cp + sigm(gi) * tanh_(gg);
        float hn = sigm(go) * tanh_(cn);
        c_reg[u][reg] = cn;
        int r = (reg & 3) + 8 * (reg >> 2) + 4 * khB;
        size_t ob = ((size_t)b * NAG + agent0 + r) * HD + hd;
        out[ob] = hn;
        out[CYS + ob] = cn;
        hnxt[r * 512 + (hd ^ ((r & 31) << 3))] = f2bf(hn);
      }
    }
    __syncthreads();
  }
}

extern "C" void kernel_launch(void* const* d_in, const int* in_sizes, int n_in,
                              void* d_out, int out_size, void* d_ws, size_t ws_size,
                              hipStream_t stream) {
  (void)in_sizes; (void)n_in; (void)out_size;
  const float* hxs     = (const float*)d_in[1];
  const float* cxs     = (const float*)d_in[2];
  const float* h_self  = (const float*)d_in[3];
  const float* h_inter = (const float*)d_in[4];
  const int*   reset   = (const int*)d_in[5];
  const float* Wih     = (const float*)d_in[6];
  const float* Whh     = (const float*)d_in[7];
  const float* bih     = (const float*)d_in[8];
  const float* bhh     = (const float*)d_in[9];
  float* out = (float*)d_out;

  const size_t needW = (size_t)2048 * 1024 * sizeof(unsigned short);  // 4 MB
  const size_t need  = needW + 8192;

  if (d_ws != nullptr && ws_size >= need) {
    unsigned short* Wpk  = (unsigned short*)d_ws;
    float*          bsum = (float*)((char*)d_ws + needW);
    prep_pack32<<<4096, 64, 0, stream>>>(Wih, Whh, bih, bhh, Wpk, bsum);
    lstm_d8<true><<<256, 512, 0, stream>>>(hxs, cxs, h_self, h_inter, reset,
                                           Wpk, bsum, Wih, Whh, bih, bhh, out);
  } else {
    lstm_d8<false><<<256, 512, 0, stream>>>(hxs, cxs, h_self, h_inter, reset,
                                            nullptr, nullptr, Wih, Whh, bih, bhh, out);
  }
}

// Round 7
// 1348.208 us; speedup vs baseline: 1.4408x; 1.4122x over previous
//
#include <hip/hip_runtime.h>

typedef __attribute__((ext_vector_type(8))) short bf16x8;
typedef __attribute__((ext_vector_type(16))) float f32x16;

#define SEQ 16
#define NAG 128
#define HD  512

__device__ __forceinline__ unsigned short f2bf(float x) {
  unsigned int u = __float_as_uint(x);
  return (unsigned short)((u + 0x7fffu + ((u >> 16) & 1u)) >> 16);  // RNE
}
__device__ __forceinline__ float sigm(float x) { return 1.0f / (1.0f + __expf(-x)); }
__device__ __forceinline__ float tanh_(float x) { return 2.0f / (1.0f + __expf(-2.0f * x)) - 1.0f; }

// Pack weights into 32x32 MFMA-B-fragment order:
//   Wpk[tile*32768 + (ks*64 + lane)*8 + e]
//   col = tile*32 + (lane&31), k = ks*16 + (lane>>5)*8 + e ; tile in [0,64), ks in [0,64)
//   k < 512 -> W_ih[:,k], else W_hh[:,k-512].  bsum[n] = b_ih[n]+b_hh[n].
__global__ void prep_pack32(const float* __restrict__ Wih, const float* __restrict__ Whh,
                            const float* __restrict__ bih, const float* __restrict__ bhh,
                            unsigned short* __restrict__ Wpk, float* __restrict__ bsum) {
  const int t  = blockIdx.x >> 6;
  const int ks = blockIdx.x & 63;
  const int l  = threadIdx.x;
  const int n  = t * 32 + (l & 31);
  const int k  = ks * 16 + (l >> 5) * 8;
  const float* p = (k < 512) ? (Wih + (size_t)n * 512 + k) : (Whh + (size_t)n * 512 + (k - 512));
  float4 w0 = *(const float4*)p;
  float4 w1 = *(const float4*)(p + 4);
  bf16x8 v = {(short)f2bf(w0.x), (short)f2bf(w0.y), (short)f2bf(w0.z), (short)f2bf(w0.w),
              (short)f2bf(w1.x), (short)f2bf(w1.y), (short)f2bf(w1.z), (short)f2bf(w1.w)};
  *(bf16x8*)(Wpk + ((size_t)blockIdx.x * 64 + l) * 8) = v;
  if (ks == 0 && l < 32) bsum[n] = bih[n] + bhh[n];
}

template <bool PACKED>
__device__ __forceinline__ bf16x8 loadBf(const float* __restrict__ Wih,
                                         const float* __restrict__ Whh,
                                         int tile, int ks, int lane) {
  int n = tile * 32 + (lane & 31);
  int k = ks * 16 + (lane >> 5) * 8;
  const float* p = (k < 512) ? (Wih + (size_t)n * 512 + k) : (Whh + (size_t)n * 512 + (k - 512));
  float4 w0 = *(const float4*)p;
  float4 w1 = *(const float4*)(p + 4);
  return bf16x8{(short)f2bf(w0.x), (short)f2bf(w0.y), (short)f2bf(w0.z), (short)f2bf(w0.w),
                (short)f2bf(w1.x), (short)f2bf(w1.y), (short)f2bf(w1.z), (short)f2bf(w1.w)};
}

// 1 block/CU (LDS 96KB). Depth-4 B queue (fits ~128-VGPR arch budget, no scratch).
// k-loop start rotated per block to de-phase the XCD-wide synchronized weight
// stream (L2 slice hotspot fix). Sum reorder only; numerics within tolerance.
template <bool PACKED>
__global__ __launch_bounds__(512, 1)
void lstm_rot(const float* __restrict__ hxs, const float* __restrict__ cxs,
              const float* __restrict__ h_self, const float* __restrict__ h_inter,
              const int* __restrict__ reset,
              const unsigned short* __restrict__ Wpk, const float* __restrict__ bsum,
              const float* __restrict__ Wih, const float* __restrict__ Whh,
              const float* __restrict__ bih, const float* __restrict__ bhh,
              float* __restrict__ out) {
  __shared__ __align__(16) unsigned short x_lds[32 * 512];      // 32 KB
  __shared__ __align__(16) unsigned short h_lds[2][32 * 512];   // 64 KB

  const int tid  = threadIdx.x;
  const int w    = tid >> 6;
  const int lane = tid & 63;
  const int colB = lane & 31;
  const int khB  = lane >> 5;
  const int row  = colB;                 // A-row this lane reads
  const int asw  = (row & 31) << 3;      // full 32-row XOR swizzle (0 conflicts)

  const int bid = blockIdx.x, traj = bid >> 2, agent0 = (bid & 3) * 32;
  const int start = ((bid >> 3) << 1) & 63;   // per-block k-phase rotation
  const int rS = tid >> 4, l16 = tid & 15;
  const int swS = (rS & 31) << 3;
  const size_t CYS = (size_t)SEQ * 64 * NAG * HD;  // 67108864

  { // stage h(0) from hxs
    const float* src = hxs + ((size_t)traj * SEQ * NAG + (agent0 + rS)) * HD;
    #pragma unroll
    for (int p = 0; p < 8; ++p) {
      int k = p * 64 + l16 * 4;
      float4 v = *(const float4*)(src + k);
      *(ushort4*)&h_lds[0][rS * 512 + (k ^ swS)] =
          make_ushort4(f2bf(v.x), f2bf(v.y), f2bf(v.z), f2bf(v.w));
    }
  }

  // persistent per-lane state
  float c_reg[2][16];
  float biasv[2][4];
  {
    #pragma unroll
    for (int u = 0; u < 2; ++u)
      #pragma unroll
      for (int q = 0; q < 4; ++q) {
        int n = q * 512 + w * 64 + u * 32 + colB;
        biasv[u][q] = PACKED ? bsum[n] : (bih[n] + bhh[n]);
      }
    const size_t cbase = ((size_t)traj * SEQ * NAG + agent0) * HD;
    #pragma unroll
    for (int u = 0; u < 2; ++u)
      #pragma unroll
      for (int reg = 0; reg < 16; ++reg) {
        int r = (reg & 3) + 8 * (reg >> 2) + 4 * khB;
        c_reg[u][reg] = cxs[cbase + (size_t)r * HD + w * 64 + u * 32 + colB];
      }
  }

  for (int t = 0; t < SEQ; ++t) {
    const int b  = traj * SEQ + t;
    const int mt = 1 - reset[b];
    const unsigned short* hcur = h_lds[t & 1];
    unsigned short*       hnxt = h_lds[(t & 1) ^ 1];

    { // stage x(t) = [h_self[b][:,256:] | h_inter[b]] -> bf16
      const float* srcs = h_self  + ((size_t)b * NAG + (agent0 + rS)) * HD + 256;
      const float* srci = h_inter + ((size_t)b * NAG + (agent0 + rS)) * 256;
      #pragma unroll
      for (int p = 0; p < 8; ++p) {
        int k = p * 64 + l16 * 4;
        const float* sp = (k < 256) ? (srcs + k) : (srci + (k - 256));
        float4 v = *(const float4*)sp;
        *(ushort4*)&x_lds[rS * 512 + (k ^ swS)] =
            make_ushort4(f2bf(v.x), f2bf(v.y), f2bf(v.z), f2bf(v.w));
      }
      if (mt == 0) {  // h input of this step is exactly zero
        uint4* pz = (uint4*)h_lds[t & 1];
        #pragma unroll
        for (int i = 0; i < 4; ++i) pz[tid + i * 512] = uint4{0, 0, 0, 0};
      }
    }
    __syncthreads();

    // A-fragment at physical k-step (selects x vs h buffer)
    auto lda = [&](int phys) -> bf16x8 {
      const unsigned short* src = (phys < 32) ? x_lds : hcur;
      int kk = (phys & 31) * 16 + khB * 8;
      return *(const bf16x8*)(src + row * 512 + (kk ^ asw));
    };

    #pragma unroll
    for (int u = 0; u < 2; ++u) {
      const int t0 = w * 2 + u, t1 = 16 + w * 2 + u, t2 = 32 + w * 2 + u, t3 = 48 + w * 2 + u;
      f32x16 acc[4];
      #pragma unroll
      for (int q = 0; q < 4; ++q)
        #pragma unroll
        for (int e = 0; e < 16; ++e) acc[q][e] = biasv[u][q];

      bf16x8 Bq[4][4];  // depth-4 prefetch queue, statically indexed only
      auto ldB = [&](bf16x8* B, int ks) {
        if (PACKED) {
          const size_t off = ((size_t)ks * 64 + lane) * 8;
          B[0] = *(const bf16x8*)(Wpk + (size_t)t0 * 32768 + off);
          B[1] = *(const bf16x8*)(Wpk + (size_t)t1 * 32768 + off);
          B[2] = *(const bf16x8*)(Wpk + (size_t)t2 * 32768 + off);
          B[3] = *(const bf16x8*)(Wpk + (size_t)t3 * 32768 + off);
        } else {
          B[0] = loadBf<PACKED>(Wih, Whh, t0, ks, lane);
          B[1] = loadBf<PACKED>(Wih, Whh, t1, ks, lane);
          B[2] = loadBf<PACKED>(Wih, Whh, t2, ks, lane);
          B[3] = loadBf<PACKED>(Wih, Whh, t3, ks, lane);
        }
      };

      // prologue: fill queue with logical 0..3 (physical start..start+3)
      #pragma unroll
      for (int d = 0; d < 4; ++d) ldB(Bq[d], (start + d) & 63);

      // steady state: logical i = kp*4+d, prefetch i+4; last block drains
      #pragma unroll 1
      for (int kp = 0; kp < 15; ++kp) {
        #pragma unroll
        for (int d = 0; d < 4; ++d) {
          const int i = kp * 4 + d;
          bf16x8 a = lda((i + start) & 63);
          __builtin_amdgcn_s_setprio(1);
          acc[0] = __builtin_amdgcn_mfma_f32_32x32x16_bf16(a, Bq[d][0], acc[0], 0, 0, 0);
          acc[1] = __builtin_amdgcn_mfma_f32_32x32x16_bf16(a, Bq[d][1], acc[1], 0, 0, 0);
          acc[2] = __builtin_amdgcn_mfma_f32_32x32x16_bf16(a, Bq[d][2], acc[2], 0, 0, 0);
          acc[3] = __builtin_amdgcn_mfma_f32_32x32x16_bf16(a, Bq[d][3], acc[3], 0, 0, 0);
          __builtin_amdgcn_s_setprio(0);
          ldB(Bq[d], (i + 4 + start) & 63);
        }
      }
      #pragma unroll
      for (int d = 0; d < 4; ++d) {  // tail: logical 60..63, drain
        const int i = 60 + d;
        bf16x8 a = lda((i + start) & 63);
        __builtin_amdgcn_s_setprio(1);
        acc[0] = __builtin_amdgcn_mfma_f32_32x32x16_bf16(a, Bq[d][0], acc[0], 0, 0, 0);
        acc[1] = __builtin_amdgcn_mfma_f32_32x32x16_bf16(a, Bq[d][1], acc[1], 0, 0, 0);
        acc[2] = __builtin_amdgcn_mfma_f32_32x32x16_bf16(a, Bq[d][2], acc[2], 0, 0, 0);
        acc[3] = __builtin_amdgcn_mfma_f32_32x32x16_bf16(a, Bq[d][3], acc[3], 0, 0, 0);
        __builtin_amdgcn_s_setprio(0);
      }

      // LSTM cell: lane-local i/f/g/o at same (row, hd); bias already in acc
      const int hd = w * 64 + u * 32 + colB;
      #pragma unroll
      for (int reg = 0; reg < 16; ++reg) {
        float gi = acc[0][reg], gf = acc[1][reg], gg = acc[2][reg], go = acc[3][reg];
        float cp = mt ? c_reg[u][reg] : 0.0f;
        float cn = sigm(gf) * cp + sigm(gi) * tanh_(gg);
        float hn = sigm(go) * tanh_(cn);
        c_reg[u][reg] = cn;
        int r = (reg & 3) + 8 * (reg >> 2) + 4 * khB;
        size_t ob = ((size_t)b * NAG + agent0 + r) * HD + hd;
        out[ob] = hn;
        out[CYS + ob] = cn;
        hnxt[r * 512 + (hd ^ ((r & 31) << 3))] = f2bf(hn);
      }
    }
    __syncthreads();
  }
}

extern "C" void kernel_launch(void* const* d_in, const int* in_sizes, int n_in,
                              void* d_out, int out_size, void* d_ws, size_t ws_size,
                              hipStream_t stream) {
  (void)in_sizes; (void)n_in; (void)out_size;
  const float* hxs     = (const float*)d_in[1];
  const float* cxs     = (const float*)d_in[2];
  const float* h_self  = (const float*)d_in[3];
  const float* h_inter = (const float*)d_in[4];
  const int*   reset   = (const int*)d_in[5];
  const float* Wih     = (const float*)d_in[6];
  const float* Whh     = (const float*)d_in[7];
  const float* bih     = (const float*)d_in[8];
  const float* bhh     = (const float*)d_in[9];
  float* out = (float*)d_out;

  const size_t needW = (size_t)2048 * 1024 * sizeof(unsigned short);  // 4 MB
  const size_t need  = needW + 8192;

  if (d_ws != nullptr && ws_size >= need) {
    unsigned short* Wpk  = (unsigned short*)d_ws;
    float*          bsum = (float*)((char*)d_ws + needW);
    prep_pack32<<<4096, 64, 0, stream>>>(Wih, Whh, bih, bhh, Wpk, bsum);
    lstm_rot<true><<<256, 512, 0, stream>>>(hxs, cxs, h_self, h_inter, reset,
                                            Wpk, bsum, Wih, Whh, bih, bhh, out);
  } else {
    lstm_rot<false><<<256, 512, 0, stream>>>(hxs, cxs, h_self, h_inter, reset,
                                             nullptr, nullptr, Wih, Whh, bih, bhh, out);
  }
}

// Round 8
// 1093.321 us; speedup vs baseline: 1.7767x; 1.2331x over previous
//
#include <hip/hip_runtime.h>

typedef __attribute__((ext_vector_type(8))) short bf16x8;
typedef __attribute__((ext_vector_type(8))) unsigned short u16x8;
typedef __attribute__((ext_vector_type(16))) float f32x16;

#define SEQ 16
#define NAG 128
#define HD  512

__device__ __forceinline__ unsigned short f2bf(float x) {
  unsigned int u = __float_as_uint(x);
  return (unsigned short)((u + 0x7fffu + ((u >> 16) & 1u)) >> 16);  // RNE
}
__device__ __forceinline__ float sigm(float x) { return 1.0f / (1.0f + __expf(-x)); }
__device__ __forceinline__ float tanh_(float x) { return 2.0f / (1.0f + __expf(-2.0f * x)) - 1.0f; }

// Pack weights into 32x32 MFMA-B-fragment order:
//   Wpk[tile*32768 + (ks*64 + lane)*8 + e]
//   col = tile*32 + (lane&31), k = ks*16 + (lane>>5)*8 + e ; tile in [0,64), ks in [0,64)
//   k < 512 -> W_ih[:,k], else W_hh[:,k-512].  bsum[n] = b_ih[n]+b_hh[n].
__global__ void prep_pack32(const float* __restrict__ Wih, const float* __restrict__ Whh,
                            const float* __restrict__ bih, const float* __restrict__ bhh,
                            unsigned short* __restrict__ Wpk, float* __restrict__ bsum) {
  const int t  = blockIdx.x >> 6;
  const int ks = blockIdx.x & 63;
  const int l  = threadIdx.x;
  const int n  = t * 32 + (l & 31);
  const int k  = ks * 16 + (l >> 5) * 8;
  const float* p = (k < 512) ? (Wih + (size_t)n * 512 + k) : (Whh + (size_t)n * 512 + (k - 512));
  float4 w0 = *(const float4*)p;
  float4 w1 = *(const float4*)(p + 4);
  bf16x8 v = {(short)f2bf(w0.x), (short)f2bf(w0.y), (short)f2bf(w0.z), (short)f2bf(w0.w),
              (short)f2bf(w1.x), (short)f2bf(w1.y), (short)f2bf(w1.z), (short)f2bf(w1.w)};
  *(bf16x8*)(Wpk + ((size_t)blockIdx.x * 64 + l) * 8) = v;
  if (ks == 0 && l < 32) bsum[n] = bih[n] + bhh[n];
}

// ---------------- per-timestep kernel (recurrence via kernel boundary) -------
// grid 256 = 64 traj x 4 hd-slices (ns = bid&3 -> one weight slice per XCD).
// Block: 128 rows (all agents of one traj) x 512 gate-cols {q*512 + ns*128 + j}.
// h(t-1), c(t-1) read from out (f32) at step t-1; step 0 reads hxs/cxs.
__global__ __launch_bounds__(512, 1)
void lstm_step(const int t,
               const float* __restrict__ hxs, const float* __restrict__ cxs,
               const float* __restrict__ h_self, const float* __restrict__ h_inter,
               const int* __restrict__ reset,
               const unsigned short* __restrict__ Wpk, const float* __restrict__ bsum,
               float* out) {
  __shared__ __align__(16) unsigned short abuf[2][128 * 256];  // 2 x 64 KB

  const int tid  = threadIdx.x;
  const int w    = tid >> 6;
  const int lane = tid & 63;
  const int c32  = lane & 31;
  const int kh   = lane >> 5;
  const int wr   = w >> 2;      // row-half (0..1)
  const int wc   = w & 3;       // col-group (0..3)

  const int bid  = blockIdx.x;
  const int ns   = bid & 3;     // hd-slice; constant per XCD (bid%8)
  const int traj = bid >> 2;    // 0..63
  const int b    = traj * SEQ + t;
  const int mt   = 1 - reset[b];
  const bool first = (t == 0);
  const size_t CYS = (size_t)SEQ * 64 * NAG * HD;  // 67108864

  // staging mapping: 512 threads -> 128 rows x 4 k-quarters (64 k each)
  const int rS = tid >> 2;
  const int q4 = tid & 3;

  auto stage = [&](int kc, int bufi) {
    unsigned short* dst = abuf[bufi];
    const int swr = (rS & 31) << 3;
    if (kc < 2) {  // x: kc0 = h_self[...,256:512), kc1 = h_inter[...,0:256)
      const float* src = (kc == 0)
          ? h_self  + ((size_t)b * NAG + rS) * HD + 256
          : h_inter + ((size_t)b * NAG + rS) * 256;
      #pragma unroll
      for (int p = 0; p < 8; ++p) {
        int kl = q4 * 64 + p * 8;
        float4 v0 = *(const float4*)(src + kl);
        float4 v1 = *(const float4*)(src + kl + 4);
        u16x8 u = {f2bf(v0.x), f2bf(v0.y), f2bf(v0.z), f2bf(v0.w),
                   f2bf(v1.x), f2bf(v1.y), f2bf(v1.z), f2bf(v1.w)};
        *(u16x8*)&dst[rS * 256 + (kl ^ swr)] = u;
      }
    } else {       // h(t-1), masked
      const int hk0 = (kc - 2) * 256;
      const float* src = first
          ? hxs + ((size_t)b * NAG + rS) * HD + hk0
          : out + ((size_t)(b - 1) * NAG + rS) * HD + hk0;  // hys section
      #pragma unroll
      for (int p = 0; p < 8; ++p) {
        int kl = q4 * 64 + p * 8;
        u16x8 u = {0, 0, 0, 0, 0, 0, 0, 0};
        if (mt) {
          float4 v0 = *(const float4*)(src + kl);
          float4 v1 = *(const float4*)(src + kl + 4);
          u = u16x8{f2bf(v0.x), f2bf(v0.y), f2bf(v0.z), f2bf(v0.w),
                    f2bf(v1.x), f2bf(v1.y), f2bf(v1.z), f2bf(v1.w)};
        }
        *(u16x8*)&dst[rS * 256 + (kl ^ swr)] = u;
      }
    }
  };

  // accumulators (bias folded into init) — 8 x f32x16 (AGPR side)
  const int hd = ns * 128 + wc * 32 + c32;
  f32x16 acc[2][4];
  #pragma unroll
  for (int q = 0; q < 4; ++q) {
    float bq = bsum[q * 512 + hd];
    #pragma unroll
    for (int rt = 0; rt < 2; ++rt)
      #pragma unroll
      for (int e = 0; e < 16; ++e) acc[rt][q][e] = bq;
  }

  // B fragment bases: tiles {q*16 + ns*4 + wc}
  const unsigned short* Wt[4];
  #pragma unroll
  for (int q = 0; q < 4; ++q) Wt[q] = Wpk + (size_t)(q * 16 + ns * 4 + wc) * 32768 + (size_t)lane * 8;

  bf16x8 Bq[2][4];
  auto ldB = [&](bf16x8* B, int ks) {
    const int off = ks * 512;  // (ks*64 elems) * 8
    B[0] = *(const bf16x8*)(Wt[0] + off);
    B[1] = *(const bf16x8*)(Wt[1] + off);
    B[2] = *(const bf16x8*)(Wt[2] + off);
    B[3] = *(const bf16x8*)(Wt[3] + off);
  };
  ldB(Bq[0], 0);
  ldB(Bq[1], 1);

  stage(0, 0);
  __syncthreads();

  const int swA = c32 << 3;
  const int arow0 = wr * 64 + c32;        // rt=0 row
  const int arow1 = wr * 64 + 32 + c32;   // rt=1 row

  #pragma unroll 1
  for (int kc = 0; kc < 4; ++kc) {
    if (kc < 3) stage(kc + 1, (kc + 1) & 1);
    const unsigned short* ab = abuf[kc & 1];
    #pragma unroll 1
    for (int k2 = 0; k2 < 8; ++k2) {
      {
        const int ksl = k2 * 2;
        const int kk = ksl * 16 + kh * 8;
        bf16x8 a0 = *(const bf16x8*)&ab[arow0 * 256 + (kk ^ swA)];
        bf16x8 a1 = *(const bf16x8*)&ab[arow1 * 256 + (kk ^ swA)];
        __builtin_amdgcn_s_setprio(1);
        acc[0][0] = __builtin_amdgcn_mfma_f32_32x32x16_bf16(a0, Bq[0][0], acc[0][0], 0, 0, 0);
        acc[0][1] = __builtin_amdgcn_mfma_f32_32x32x16_bf16(a0, Bq[0][1], acc[0][1], 0, 0, 0);
        acc[0][2] = __builtin_amdgcn_mfma_f32_32x32x16_bf16(a0, Bq[0][2], acc[0][2], 0, 0, 0);
        acc[0][3] = __builtin_amdgcn_mfma_f32_32x32x16_bf16(a0, Bq[0][3], acc[0][3], 0, 0, 0);
        acc[1][0] = __builtin_amdgcn_mfma_f32_32x32x16_bf16(a1, Bq[0][0], acc[1][0], 0, 0, 0);
        acc[1][1] = __builtin_amdgcn_mfma_f32_32x32x16_bf16(a1, Bq[0][1], acc[1][1], 0, 0, 0);
        acc[1][2] = __builtin_amdgcn_mfma_f32_32x32x16_bf16(a1, Bq[0][2], acc[1][2], 0, 0, 0);
        acc[1][3] = __builtin_amdgcn_mfma_f32_32x32x16_bf16(a1, Bq[0][3], acc[1][3], 0, 0, 0);
        __builtin_amdgcn_s_setprio(0);
        int kf = kc * 16 + ksl + 2;
        if (kf < 64) ldB(Bq[0], kf);
      }
      {
        const int ksl = k2 * 2 + 1;
        const int kk = ksl * 16 + kh * 8;
        bf16x8 a0 = *(const bf16x8*)&ab[arow0 * 256 + (kk ^ swA)];
        bf16x8 a1 = *(const bf16x8*)&ab[arow1 * 256 + (kk ^ swA)];
        __builtin_amdgcn_s_setprio(1);
        acc[0][0] = __builtin_amdgcn_mfma_f32_32x32x16_bf16(a0, Bq[1][0], acc[0][0], 0, 0, 0);
        acc[0][1] = __builtin_amdgcn_mfma_f32_32x32x16_bf16(a0, Bq[1][1], acc[0][1], 0, 0, 0);
        acc[0][2] = __builtin_amdgcn_mfma_f32_32x32x16_bf16(a0, Bq[1][2], acc[0][2], 0, 0, 0);
        acc[0][3] = __builtin_amdgcn_mfma_f32_32x32x16_bf16(a0, Bq[1][3], acc[0][3], 0, 0, 0);
        acc[1][0] = __builtin_amdgcn_mfma_f32_32x32x16_bf16(a1, Bq[1][0], acc[1][0], 0, 0, 0);
        acc[1][1] = __builtin_amdgcn_mfma_f32_32x32x16_bf16(a1, Bq[1][1], acc[1][1], 0, 0, 0);
        acc[1][2] = __builtin_amdgcn_mfma_f32_32x32x16_bf16(a1, Bq[1][2], acc[1][2], 0, 0, 0);
        acc[1][3] = __builtin_amdgcn_mfma_f32_32x32x16_bf16(a1, Bq[1][3], acc[1][3], 0, 0, 0);
        __builtin_amdgcn_s_setprio(0);
        int kf = kc * 16 + ksl + 2;
        if (kf < 64) ldB(Bq[1], kf);
      }
    }
    __syncthreads();
  }

  // epilogue: cell update, lane-local i/f/g/o at same (row, hd)
  #pragma unroll
  for (int rt = 0; rt < 2; ++rt) {
    #pragma unroll
    for (int reg = 0; reg < 16; ++reg) {
      const int arow = wr * 64 + rt * 32 + ((reg & 3) + 8 * (reg >> 2) + 4 * kh);
      float cp;
      if (first) cp = cxs[((size_t)b * NAG + arow) * HD + hd];
      else       cp = out[CYS + ((size_t)(b - 1) * NAG + arow) * HD + hd];
      cp = mt ? cp : 0.0f;
      float gi = acc[rt][0][reg];
      float gf = acc[rt][1][reg];
      float gg = acc[rt][2][reg];
      float go = acc[rt][3][reg];
      float cn = sigm(gf) * cp + sigm(gi) * tanh_(gg);
      float hn = sigm(go) * tanh_(cn);
      const size_t ob = ((size_t)b * NAG + arow) * HD + hd;
      out[ob] = hn;
      out[CYS + ob] = cn;
    }
  }
}

// ---------------- fallback (R2-proven monolithic, no workspace needed) ------
__device__ __forceinline__ bf16x8 loadBf(const float* __restrict__ Wih,
                                         const float* __restrict__ Whh,
                                         int tile, int ks, int lane) {
  int n = tile * 32 + (lane & 31);
  int k = ks * 16 + (lane >> 5) * 8;
  const float* p = (k < 512) ? (Wih + (size_t)n * 512 + k) : (Whh + (size_t)n * 512 + (k - 512));
  float4 w0 = *(const float4*)p;
  float4 w1 = *(const float4*)(p + 4);
  return bf16x8{(short)f2bf(w0.x), (short)f2bf(w0.y), (short)f2bf(w0.z), (short)f2bf(w0.w),
                (short)f2bf(w1.x), (short)f2bf(w1.y), (short)f2bf(w1.z), (short)f2bf(w1.w)};
}

__global__ __launch_bounds__(512, 2)
void lstm_fb(const float* __restrict__ hxs, const float* __restrict__ cxs,
             const float* __restrict__ h_self, const float* __restrict__ h_inter,
             const int* __restrict__ reset,
             const float* __restrict__ Wih, const float* __restrict__ Whh,
             const float* __restrict__ bih, const float* __restrict__ bhh,
             float* __restrict__ out) {
  __shared__ __align__(16) unsigned short x_lds[32 * 512];
  __shared__ __align__(16) unsigned short h_lds[2][32 * 512];
  const int tid = threadIdx.x;
  const int w = tid >> 6, lane = tid & 63;
  const int colB = lane & 31, khB = lane >> 5, row = colB;
  const int asw = (row & 7) << 3;
  const int bid = blockIdx.x, traj = bid >> 2, agent0 = (bid & 3) * 32;
  const int rS = tid >> 4, l16 = tid & 15, swS = (rS & 7) << 3;
  const size_t CYS = (size_t)SEQ * 64 * NAG * HD;
  {
    const float* src = hxs + ((size_t)traj * SEQ * NAG + (agent0 + rS)) * HD;
    #pragma unroll
    for (int p = 0; p < 8; ++p) {
      int k = p * 64 + l16 * 4;
      float4 v = *(const float4*)(src + k);
      *(ushort4*)&h_lds[0][rS * 512 + (k ^ swS)] =
          make_ushort4(f2bf(v.x), f2bf(v.y), f2bf(v.z), f2bf(v.w));
    }
  }
  float c_reg[2][16];
  float biasv[2][4];
  {
    #pragma unroll
    for (int u = 0; u < 2; ++u)
      #pragma unroll
      for (int q = 0; q < 4; ++q) {
        int n = q * 512 + w * 64 + u * 32 + colB;
        biasv[u][q] = bih[n] + bhh[n];
      }
    const size_t cbase = ((size_t)traj * SEQ * NAG + agent0) * HD;
    #pragma unroll
    for (int u = 0; u < 2; ++u)
      #pragma unroll
      for (int reg = 0; reg < 16; ++reg) {
        int r = (reg & 3) + 8 * (reg >> 2) + 4 * khB;
        c_reg[u][reg] = cxs[cbase + (size_t)r * HD + w * 64 + u * 32 + colB];
      }
  }
  for (int t = 0; t < SEQ; ++t) {
    const int b = traj * SEQ + t;
    const int mt = 1 - reset[b];
    const unsigned short* hcur = h_lds[t & 1];
    unsigned short* hnxt = h_lds[(t & 1) ^ 1];
    {
      const float* srcs = h_self + ((size_t)b * NAG + (agent0 + rS)) * HD + 256;
      const float* srci = h_inter + ((size_t)b * NAG + (agent0 + rS)) * 256;
      #pragma unroll
      for (int p = 0; p < 8; ++p) {
        int k = p * 64 + l16 * 4;
        const float* sp = (k < 256) ? (srcs + k) : (srci + (k - 256));
        float4 v = *(const float4*)sp;
        *(ushort4*)&x_lds[rS * 512 + (k ^ swS)] =
            make_ushort4(f2bf(v.x), f2bf(v.y), f2bf(v.z), f2bf(v.w));
      }
      if (mt == 0) {
        uint4* pz = (uint4*)h_lds[t & 1];
        #pragma unroll
        for (int i = 0; i < 4; ++i) pz[tid + i * 512] = uint4{0, 0, 0, 0};
      }
    }
    __syncthreads();
    auto lda = [&](int ks, const unsigned short* src) -> bf16x8 {
      int kk = (ks & 31) * 16 + khB * 8;
      return *(const bf16x8*)(src + row * 512 + (kk ^ asw));
    };
    #pragma unroll
    for (int u = 0; u < 2; ++u) {
      const int t0 = w * 2 + u, t1 = 16 + w * 2 + u, t2 = 32 + w * 2 + u, t3 = 48 + w * 2 + u;
      f32x16 acc[4];
      #pragma unroll
      for (int q = 0; q < 4; ++q)
        #pragma unroll
        for (int e = 0; e < 16; ++e) acc[q][e] = biasv[u][q];
      bf16x8 Ba[4], Bb[4];
      auto ldB = [&](bf16x8* B, int ks) {
        B[0] = loadBf(Wih, Whh, t0, ks, lane);
        B[1] = loadBf(Wih, Whh, t1, ks, lane);
        B[2] = loadBf(Wih, Whh, t2, ks, lane);
        B[3] = loadBf(Wih, Whh, t3, ks, lane);
      };
      ldB(Ba, 0);
      ldB(Bb, 1);
      #pragma unroll 1
      for (int kp = 0; kp < 32; ++kp) {
        const int ks0 = kp * 2;
        const unsigned short* ab = (ks0 < 32) ? x_lds : hcur;
        bf16x8 a0 = lda(ks0, ab);
        __builtin_amdgcn_s_setprio(1);
        acc[0] = __builtin_amdgcn_mfma_f32_32x32x16_bf16(a0, Ba[0], acc[0], 0, 0, 0);
        acc[1] = __builtin_amdgcn_mfma_f32_32x32x16_bf16(a0, Ba[1], acc[1], 0, 0, 0);
        acc[2] = __builtin_amdgcn_mfma_f32_32x32x16_bf16(a0, Ba[2], acc[2], 0, 0, 0);
        acc[3] = __builtin_amdgcn_mfma_f32_32x32x16_bf16(a0, Ba[3], acc[3], 0, 0, 0);
        __builtin_amdgcn_s_setprio(0);
        ldB(Ba, (ks0 + 2 < 64) ? ks0 + 2 : 63);
        const unsigned short* ab1 = (ks0 + 1 < 32) ? x_lds : hcur;
        bf16x8 a1 = lda(ks0 + 1, ab1);
        __builtin_amdgcn_s_setprio(1);
        acc[0] = __builtin_amdgcn_mfma_f32_32x32x16_bf16(a1, Bb[0], acc[0], 0, 0, 0);
        acc[1] = __builtin_amdgcn_mfma_f32_32x32x16_bf16(a1, Bb[1], acc[1], 0, 0, 0);
        acc[2] = __builtin_amdgcn_mfma_f32_32x32x16_bf16(a1, Bb[2], acc[2], 0, 0, 0);
        acc[3] = __builtin_amdgcn_mfma_f32_32x32x16_bf16(a1, Bb[3], acc[3], 0, 0, 0);
        __builtin_amdgcn_s_setprio(0);
        ldB(Bb, (ks0 + 3 < 64) ? ks0 + 3 : 63);
      }
      const int hd = w * 64 + u * 32 + colB;
      #pragma unroll
      for (int reg = 0; reg < 16; ++reg) {
        float gi = acc[0][reg], gf = acc[1][reg], gg = acc[2][reg], go = acc[3][reg];
        float cp = mt ? c_reg[u][reg] : 0.0f;
        float cn = sigm(gf) * cp + sigm(gi) * tanh_(gg);
        float hn = sigm(go) * tanh_(cn);
        c_reg[u][reg] = cn;
        int r = (reg & 3) + 8 * (reg >> 2) + 4 * khB;
        size_t ob = ((size_t)b * NAG + agent0 + r) * HD + hd;
        out[ob] = hn;
        out[CYS + ob] = cn;
        hnxt[r * 512 + (hd ^ ((r & 7) << 3))] = f2bf(hn);
      }
    }
    __syncthreads();
  }
}

extern "C" void kernel_launch(void* const* d_in, const int* in_sizes, int n_in,
                              void* d_out, int out_size, void* d_ws, size_t ws_size,
                              hipStream_t stream) {
  (void)in_sizes; (void)n_in; (void)out_size;
  const float* hxs     = (const float*)d_in[1];
  const float* cxs     = (const float*)d_in[2];
  const float* h_self  = (const float*)d_in[3];
  const float* h_inter = (const float*)d_in[4];
  const int*   reset   = (const int*)d_in[5];
  const float* Wih     = (const float*)d_in[6];
  const float* Whh     = (const float*)d_in[7];
  const float* bih     = (const float*)d_in[8];
  const float* bhh     = (const float*)d_in[9];
  float* out = (float*)d_out;

  const size_t needW = (size_t)2048 * 1024 * sizeof(unsigned short);  // 4 MB
  const size_t need  = needW + 8192;

  if (d_ws != nullptr && ws_size >= need) {
    unsigned short* Wpk  = (unsigned short*)d_ws;
    float*          bsum = (float*)((char*)d_ws + needW);
    prep_pack32<<<4096, 64, 0, stream>>>(Wih, Whh, bih, bhh, Wpk, bsum);
    for (int t = 0; t < SEQ; ++t)
      lstm_step<<<256, 512, 0, stream>>>(t, hxs, cxs, h_self, h_inter, reset,
                                         Wpk, bsum, out);
  } else {
    lstm_fb<<<256, 512, 0, stream>>>(hxs, cxs, h_self, h_inter, reset,
                                     Wih, Whh, bih, bhh, out);
  }
}